// Round 2
// baseline (350.594 us; speedup 1.0000x reference)
//
#include <hip/hip_runtime.h>
#include <hip/hip_bf16.h>

// sqllm 4-bit GEMM: out[m,n] = sum_k A[m,k] * lut[n, nibble(qweight[k/8,n], k%8)]
// M=8192, N=4096, K=4096 (derived from in_sizes at runtime).
// Strategy: bf16 MFMA GEMM (16x16x32), 128x128 tile, BK=64, 4 waves.
// If ws_size permits (>= M*K*2 + K*N*2 bytes): prepass converts A->bf16 and
// dequantizes W once into d_ws (PRE path). Else: fused dequant in B-staging.

#define BM 128
#define BN 128
#define BK 64
#define NT 256

typedef __attribute__((ext_vector_type(4))) float  f32x4;
typedef __attribute__((ext_vector_type(4))) int    i32x4;
typedef __attribute__((ext_vector_type(8))) short  bf16x8;

__device__ __forceinline__ unsigned short f2bf(float f) {
    __hip_bfloat16 h = __float2bfloat16(f);
    return __builtin_bit_cast(unsigned short, h);
}

// XOR swizzle (G4): breaks the 16/32-way bank conflict of row-major [row][BK]
// bf16 tiles (row stride 128B) on ds_read_b128. Applied on both write & read.
__device__ __forceinline__ int swz(int row, int kb) {
    return row * (BK * 2) + (kb ^ ((row & 7) << 4));
}

// ---------------- prepass kernels (PRE path) ----------------

__global__ void convA_kernel(const float* __restrict__ in, unsigned short* __restrict__ o, long n8) {
    long i = (long)blockIdx.x * blockDim.x + threadIdx.x;
    long stride = (long)gridDim.x * blockDim.x;
    const f32x4* in4 = reinterpret_cast<const f32x4*>(in);
    bf16x8* o8 = reinterpret_cast<bf16x8*>(o);
    for (; i < n8; i += stride) {
        f32x4 a = in4[2 * i];
        f32x4 b = in4[2 * i + 1];
        bf16x8 e;
#pragma unroll
        for (int x = 0; x < 4; ++x) {
            e[x]     = (short)f2bf(a[x]);
            e[4 + x] = (short)f2bf(b[x]);
        }
        o8[i] = e;
    }
}

// Wb layout: [K/8][N][8] bf16 — prepass writes and GEMM B-tile reads both
// fully coalesced (16B per int32, consecutive lanes -> consecutive 16B).
__global__ void dequantW_kernel(const int* __restrict__ Q, const float* __restrict__ lut,
                                unsigned short* __restrict__ Wb, int N, long total) {
    long i = (long)blockIdx.x * blockDim.x + threadIdx.x;
    if (i >= total) return;
    unsigned int v = (unsigned int)Q[i];
    int n = (int)(i % N);
    const float* lp = lut + (long)n * 16;
    bf16x8 w;
#pragma unroll
    for (int p = 0; p < 8; ++p)
        w[p] = (short)f2bf(lp[(v >> (4 * p)) & 15]);
    reinterpret_cast<bf16x8*>(Wb)[i] = w;
}

// ---------------- main GEMM ----------------

template <int MODE>  // 0 = fused dequant, 1 = pre-dequantized (Abf/Wb in ws)
__global__ __launch_bounds__(NT, 2)
void sqllm_gemm(const float* __restrict__ A, const int* __restrict__ Q,
                const float* __restrict__ lut, const unsigned short* __restrict__ Abf,
                const unsigned short* __restrict__ Wb, float* __restrict__ out,
                int M, int N, int K) {
    __shared__ __align__(16) char sA[BM * BK * 2];
    __shared__ __align__(16) char sB[BN * BK * 2];
    __shared__ float sLut[MODE == 0 ? BN * 17 : 1];  // +1 pad: LUT-gather bank spread

    const int tid  = threadIdx.x;
    const int lane = tid & 63;
    const int wid  = tid >> 6;
    const int wr   = wid >> 1;   // wave row (2x2 waves, each 64x64 out)
    const int wc   = wid & 1;

    const int n0 = blockIdx.x * BN;
    const int m0 = blockIdx.y * BM;

    if (MODE == 0) {
        for (int i = tid; i < BN * 16; i += NT) {
            int n = i >> 4, c = i & 15;
            sLut[n * 17 + c] = lut[(long)(n0 + n) * 16 + c];
        }
    }
    __syncthreads();

    f32x4 acc[4][4] = {};

    const int nK = K / BK;
    for (int kk = 0; kk < nK; ++kk) {
        // ---------- stage A & B into LDS (swizzled) ----------
        {
            const int r = tid >> 1, h = tid & 1;  // A: 2 threads/row, 32 k each
            if (MODE == 0) {
                const float* ap = A + (long)(m0 + r) * K + kk * BK + h * 32;
                f32x4 v[8];
#pragma unroll
                for (int j = 0; j < 8; ++j) v[j] = reinterpret_cast<const f32x4*>(ap)[j];

                const int kr = tid >> 5, nq = (tid & 31) << 2;  // B: 4 int32/thread
                const int* qp = Q + (long)(kk * (BK / 8) + kr) * N + n0 + nq;
                i32x4 q = *reinterpret_cast<const i32x4*>(qp);

#pragma unroll
                for (int j = 0; j < 4; ++j) {
                    bf16x8 e;
#pragma unroll
                    for (int x = 0; x < 4; ++x) {
                        e[x]     = (short)f2bf(v[2 * j][x]);
                        e[4 + x] = (short)f2bf(v[2 * j + 1][x]);
                    }
                    *reinterpret_cast<bf16x8*>(sA + swz(r, h * 64 + j * 16)) = e;
                }
#pragma unroll
                for (int c = 0; c < 4; ++c) {
                    const int n = nq + c;
                    const float* lp = sLut + n * 17;
                    unsigned int qq = (unsigned int)q[c];
                    bf16x8 w;
#pragma unroll
                    for (int p = 0; p < 8; ++p)
                        w[p] = (short)f2bf(lp[(qq >> (4 * p)) & 15]);
                    *reinterpret_cast<bf16x8*>(sB + swz(n, kr * 16)) = w;
                }
            } else {
                const unsigned short* ap = Abf + (long)(m0 + r) * K + kk * BK + h * 32;
                bf16x8 av[4];
#pragma unroll
                for (int j = 0; j < 4; ++j) av[j] = reinterpret_cast<const bf16x8*>(ap)[j];

                const int kr = tid >> 5, nq = (tid & 31) << 2;
                const unsigned short* bp = Wb + ((long)(kk * (BK / 8) + kr) * N + n0 + nq) * 8;
                bf16x8 bv[4];
#pragma unroll
                for (int c = 0; c < 4; ++c) bv[c] = reinterpret_cast<const bf16x8*>(bp)[c];

#pragma unroll
                for (int j = 0; j < 4; ++j)
                    *reinterpret_cast<bf16x8*>(sA + swz(r, h * 64 + j * 16)) = av[j];
#pragma unroll
                for (int c = 0; c < 4; ++c)
                    *reinterpret_cast<bf16x8*>(sB + swz(nq + c, kr * 16)) = bv[c];
            }
        }
        __syncthreads();

        // ---------- compute: 2 k-halves x 4x4 fragments ----------
#pragma unroll
        for (int kh = 0; kh < 2; ++kh) {
            const int kb = kh * 64 + (lane >> 4) * 16;
            bf16x8 af[4], bfv[4];
#pragma unroll
            for (int i = 0; i < 4; ++i) {
                af[i]  = *reinterpret_cast<const bf16x8*>(sA + swz(wr * 64 + i * 16 + (lane & 15), kb));
                bfv[i] = *reinterpret_cast<const bf16x8*>(sB + swz(wc * 64 + i * 16 + (lane & 15), kb));
            }
#pragma unroll
            for (int i = 0; i < 4; ++i)
#pragma unroll
                for (int j = 0; j < 4; ++j)
                    acc[i][j] = __builtin_amdgcn_mfma_f32_16x16x32_bf16(af[i], bfv[j], acc[i][j], 0, 0, 0);
        }
        __syncthreads();
    }

    // ---------- epilogue: C/D layout col=lane&15, row=(lane>>4)*4+reg ----------
    const int col = lane & 15;
    const int r4  = (lane >> 4) * 4;
#pragma unroll
    for (int i = 0; i < 4; ++i) {
        const int mrow = m0 + wr * 64 + i * 16 + r4;
#pragma unroll
        for (int j = 0; j < 4; ++j) {
            const int ncol = n0 + wc * 64 + j * 16 + col;
#pragma unroll
            for (int r = 0; r < 4; ++r)
                out[(long)(mrow + r) * N + ncol] = acc[i][j][r];
        }
    }
}

extern "C" void kernel_launch(void* const* d_in, const int* in_sizes, int n_in,
                              void* d_out, int out_size, void* d_ws, size_t ws_size,
                              hipStream_t stream) {
    const float* A   = (const float*)d_in[0];
    const int*   Q   = (const int*)d_in[1];
    const float* lut = (const float*)d_in[2];
    float* out = (float*)d_out;

    const long szA = in_sizes[0], szQ = in_sizes[1], szL = in_sizes[2];
    const int N = (int)(szL / 16);
    const int K = (int)(szQ * 8 / N);
    const int M = (int)(szA / K);

    const size_t needA = (size_t)M * K * 2;
    const size_t needW = (size_t)K * N * 2;

    dim3 grid(N / BN, M / BM);

    if (ws_size >= needA + needW) {
        unsigned short* Abf = (unsigned short*)d_ws;
        unsigned short* Wb  = (unsigned short*)((char*)d_ws + needA);
        const long n8 = (long)M * K / 8;
        convA_kernel<<<2048, 256, 0, stream>>>(A, Abf, n8);
        const long tq = (long)(K / 8) * N;
        dequantW_kernel<<<(int)((tq + 255) / 256), 256, 0, stream>>>(Q, lut, Wb, N, tq);
        sqllm_gemm<1><<<grid, NT, 0, stream>>>(A, Q, lut, Abf, Wb, out, M, N, K);
    } else {
        sqllm_gemm<0><<<grid, NT, 0, stream>>>(A, Q, lut, nullptr, nullptr, out, M, N, K);
    }
}

// Round 3
// 301.614 us; speedup vs baseline: 1.1624x; 1.1624x over previous
//
#include <hip/hip_runtime.h>
#include <hip/hip_bf16.h>

// sqllm 4-bit GEMM: out[m,n] = sum_k A[m,k] * lut[n, nibble(qweight[k/8,n], k%8)]
// M=8192, N=4096, K=4096. PRE path: A->bf16, W dequant once into ws, then
// 256x256 8-phase MFMA GEMM (T2 swizzle + T3/T4 counted vmcnt + T5 setprio).

typedef __attribute__((ext_vector_type(4))) float  f32x4;
typedef __attribute__((ext_vector_type(4))) int    i32x4;
typedef __attribute__((ext_vector_type(8))) short  bf16x8;

__device__ __forceinline__ unsigned short f2bf(float f) {
    __hip_bfloat16 h = __float2bfloat16(f);
    return __builtin_bit_cast(unsigned short, h);
}

__device__ __forceinline__ void gload16(const unsigned short* g, unsigned short* l) {
    __builtin_amdgcn_global_load_lds(
        (const __attribute__((address_space(1))) unsigned int*)g,
        (__attribute__((address_space(3))) unsigned int*)l, 16, 0, 0);
}

// ---------------- prepass kernels ----------------

__global__ void convA_kernel(const float* __restrict__ in, unsigned short* __restrict__ o, long n8) {
    long i = (long)blockIdx.x * blockDim.x + threadIdx.x;
    long stride = (long)gridDim.x * blockDim.x;
    const f32x4* in4 = reinterpret_cast<const f32x4*>(in);
    bf16x8* o8 = reinterpret_cast<bf16x8*>(o);
    for (; i < n8; i += stride) {
        f32x4 a = in4[2 * i];
        f32x4 b = in4[2 * i + 1];
        bf16x8 e;
#pragma unroll
        for (int x = 0; x < 4; ++x) {
            e[x]     = (short)f2bf(a[x]);
            e[4 + x] = (short)f2bf(b[x]);
        }
        o8[i] = e;
    }
}

// Wb layout: [K/8][N][8] bf16 — prepass write and GEMM staging both coalesced.
__global__ void dequantW_kernel(const int* __restrict__ Q, const float* __restrict__ lut,
                                unsigned short* __restrict__ Wb, int N, long total) {
    long i = (long)blockIdx.x * blockDim.x + threadIdx.x;
    if (i >= total) return;
    unsigned int v = (unsigned int)Q[i];
    int n = (int)(i % N);
    const float* lp = lut + (long)n * 16;
    bf16x8 w;
#pragma unroll
    for (int p = 0; p < 8; ++p)
        w[p] = (short)f2bf(lp[(v >> (4 * p)) & 15]);
    reinterpret_cast<bf16x8*>(Wb)[i] = w;
}

// ---------------- 256x256 8-phase GEMM ----------------
// 8 waves (2M x 4N), per-wave 128x64 out. LDS: 4-slot ring of K-half (32-k)
// buffers per matrix, 16KB each (A: [m(256)][kc(4) swizzled][8], B: [kc(4)][n(256)][8]).
// Slot for (tile t, khalf h) = (2t+h)&3. Phases q0/q1 read kh0, q2/q3 read kh1.
// Prefetch issued 5-6 phases ahead of first read; vmcnt(8) (=2 loads x 4 newer
// half-tiles) guarantees the needed half landed. Never vmcnt(0) in the loop.

#define VM8 asm volatile("s_waitcnt vmcnt(8)" ::: "memory")

#define MFMA4(MF, AF) \
    acc[MF][0] = __builtin_amdgcn_mfma_f32_16x16x32_bf16(AF, bv0, acc[MF][0], 0, 0, 0); \
    acc[MF][1] = __builtin_amdgcn_mfma_f32_16x16x32_bf16(AF, bv1, acc[MF][1], 0, 0, 0); \
    acc[MF][2] = __builtin_amdgcn_mfma_f32_16x16x32_bf16(AF, bv2, acc[MF][2], 0, 0, 0); \
    acc[MF][3] = __builtin_amdgcn_mfma_f32_16x16x32_bf16(AF, bv3, acc[MF][3], 0, 0, 0);

#define DO_PHASE(SA, SB, MH, STAGE, WAIT) do {                                  \
    bf16x8 av0 = *(const bf16x8*)((SA) + aoff + (MH * 4 + 0) * 512);            \
    bf16x8 av1 = *(const bf16x8*)((SA) + aoff + (MH * 4 + 1) * 512);            \
    bf16x8 av2 = *(const bf16x8*)((SA) + aoff + (MH * 4 + 2) * 512);            \
    bf16x8 av3 = *(const bf16x8*)((SA) + aoff + (MH * 4 + 3) * 512);            \
    bf16x8 bv0 = *(const bf16x8*)((SB) + boff + 0 * 128);                       \
    bf16x8 bv1 = *(const bf16x8*)((SB) + boff + 1 * 128);                       \
    bf16x8 bv2 = *(const bf16x8*)((SB) + boff + 2 * 128);                       \
    bf16x8 bv3 = *(const bf16x8*)((SB) + boff + 3 * 128);                       \
    STAGE;                                                                      \
    WAIT;                                                                       \
    __builtin_amdgcn_s_barrier();                                               \
    __builtin_amdgcn_s_setprio(1);                                              \
    MFMA4(MH * 4 + 0, av0)                                                      \
    MFMA4(MH * 4 + 1, av1)                                                      \
    MFMA4(MH * 4 + 2, av2)                                                      \
    MFMA4(MH * 4 + 3, av3)                                                      \
    __builtin_amdgcn_s_setprio(0);                                              \
    __builtin_amdgcn_s_barrier();                                               \
} while (0)

__global__ __launch_bounds__(512, 2)
void gemm8p(const unsigned short* __restrict__ Abf, const unsigned short* __restrict__ Wb,
            float* __restrict__ out, int M, int N, int K) {
    __shared__ __align__(16) unsigned short sA[4 * 8192];  // 64 KB: 4 slots x 256m x 32k
    __shared__ __align__(16) unsigned short sB[4 * 8192];  // 64 KB: 4 slots x 4kc x 256n x 8

    const int tid  = threadIdx.x;
    const int lane = tid & 63;
    const int wid  = tid >> 6;
    const int wr   = wid >> 2;   // 0..1  (128-row half)
    const int wc   = wid & 3;    // 0..3  (64-col slice)
    const int r15  = lane & 15;
    const int hi   = lane >> 4;

    // XCD-aware bijective swizzle (nwg % 8 == 0 here)
    int nwg = gridDim.x, orig = blockIdx.x;
    int wg = ((nwg & 7) == 0) ? (orig & 7) * (nwg >> 3) + (orig >> 3) : orig;
    const int NBN = N / 256;
    const int m0 = (wg / NBN) * 256, n0 = (wg % NBN) * 256;

    const int KT = K / 64;

    // per-lane ds_read bases (ushort elements)
    // A frag: row = wr*128 + mf*16 + r15, k-chunk hi (XOR-swizzled by ((row>>1)&3))
    const int aoff = (wr * 128 + r15) * 32 + ((hi ^ ((r15 >> 1) & 3)) << 3);
    // B frag: [kc=hi][n = wc*64 + nf*16 + r15][8]
    const int boff = hi * 2048 + (wc * 64 + r15) * 8;

    // staging: half-tile (tile tau, khalf kh) -> ring slot; 2 x gload16/thread
    auto stageA = [&](int tau, int kh, int slot) {
#pragma unroll
        for (int j = 0; j < 2; ++j) {
            int idx = j * 512 + tid;
            int m = idx >> 2, kc = idx & 3;
            const unsigned short* src = Abf + (size_t)(m0 + m) * K + tau * 64 + kh * 32
                                        + ((kc ^ ((m >> 1) & 3)) << 3);
            gload16(src, sA + slot * 8192 + j * 4096 + wid * 512);
        }
    };
    auto stageB = [&](int tau, int kh, int slot) {
#pragma unroll
        for (int j = 0; j < 2; ++j) {
            int idx = j * 512 + tid;
            int kc = idx >> 8, n = idx & 255;
            const unsigned short* src = Wb + ((size_t)(tau * 8 + kh * 4 + kc) * N + n0 + n) * 8;
            gload16(src, sB + slot * 8192 + j * 4096 + wid * 512);
        }
    };

    f32x4 acc[8][4] = {};

    // prologue: tile0 kh0, tile0 kh1, tile1 kh0 (12 loads); oldest 4 = tile0 kh0
    stageA(0, 0, 0); stageB(0, 0, 0);
    stageA(0, 1, 1); stageB(0, 1, 1);
    stageA(1, 0, 2); stageB(1, 0, 2);
    VM8;
    __builtin_amdgcn_s_barrier();

    const unsigned short* A0 = sA + 0 * 8192; const unsigned short* B0 = sB + 0 * 8192;
    const unsigned short* A1 = sA + 1 * 8192; const unsigned short* B1 = sB + 1 * 8192;
    const unsigned short* A2 = sA + 2 * 8192; const unsigned short* B2 = sB + 2 * 8192;
    const unsigned short* A3 = sA + 3 * 8192; const unsigned short* B3 = sB + 3 * 8192;

    for (int t = 0; t < KT; t += 2) {
        const int ta = t + 1;                                    // odd, no wrap
        const int tb = (t + 2 == KT) ? 0 : t + 2;                // even (KT even)
        const int tc = (t + 3 >= KT) ? (t + 3 - KT) : t + 3;     // odd
        // tile t (even): kh0 -> slot0, kh1 -> slot1
        DO_PHASE(A0, B0, 0, stageA(ta, 1, 3), );
        DO_PHASE(A0, B0, 1, stageB(ta, 1, 3), VM8);
        DO_PHASE(A1, B1, 0, stageA(tb, 0, 0), );
        DO_PHASE(A1, B1, 1, stageB(tb, 0, 0), VM8);
        // tile t+1 (odd): kh0 -> slot2, kh1 -> slot3
        DO_PHASE(A2, B2, 0, stageA(tb, 1, 1), );
        DO_PHASE(A2, B2, 1, stageB(tb, 1, 1), VM8);
        DO_PHASE(A3, B3, 0, stageA(tc, 0, 2), );
        DO_PHASE(A3, B3, 1, stageB(tc, 0, 2), VM8);
    }

    asm volatile("s_waitcnt vmcnt(0)" ::: "memory");  // drain wrap-around prefetches

    // epilogue: C/D layout col=lane&15, row=(lane>>4)*4+reg
#pragma unroll
    for (int mf = 0; mf < 8; ++mf) {
        const int mrow = m0 + wr * 128 + mf * 16 + hi * 4;
#pragma unroll
        for (int nf = 0; nf < 4; ++nf) {
            const int ncol = n0 + wc * 64 + nf * 16 + r15;
            float* po = out + (size_t)mrow * N + ncol;
#pragma unroll
            for (int r = 0; r < 4; ++r) po[(size_t)r * N] = acc[mf][nf][r];
        }
    }
}

// ---------------- fallback fused kernel (small ws only) ----------------

#define FBM 128
#define FBN 128
#define FBK 64

__device__ __forceinline__ int fswz(int row, int kb) {
    return row * (FBK * 2) + (kb ^ ((row & 7) << 4));
}

__global__ __launch_bounds__(256, 2)
void sqllm_gemm_fused(const float* __restrict__ A, const int* __restrict__ Q,
                      const float* __restrict__ lut, float* __restrict__ out,
                      int M, int N, int K) {
    __shared__ __align__(16) char sA[FBM * FBK * 2];
    __shared__ __align__(16) char sB[FBN * FBK * 2];
    __shared__ float sLut[FBN * 17];

    const int tid  = threadIdx.x;
    const int lane = tid & 63;
    const int wid  = tid >> 6;
    const int wr   = wid >> 1;
    const int wc   = wid & 1;
    const int n0 = blockIdx.x * FBN;
    const int m0 = blockIdx.y * FBM;

    for (int i = tid; i < FBN * 16; i += 256) {
        int n = i >> 4, c = i & 15;
        sLut[n * 17 + c] = lut[(long)(n0 + n) * 16 + c];
    }
    __syncthreads();

    f32x4 acc[4][4] = {};
    const int nK = K / FBK;
    for (int kk = 0; kk < nK; ++kk) {
        {
            const int r = tid >> 1, h = tid & 1;
            const float* ap = A + (long)(m0 + r) * K + kk * FBK + h * 32;
            f32x4 v[8];
#pragma unroll
            for (int j = 0; j < 8; ++j) v[j] = reinterpret_cast<const f32x4*>(ap)[j];
            const int kr = tid >> 5, nq = (tid & 31) << 2;
            const int* qp = Q + (long)(kk * (FBK / 8) + kr) * N + n0 + nq;
            i32x4 q = *reinterpret_cast<const i32x4*>(qp);
#pragma unroll
            for (int j = 0; j < 4; ++j) {
                bf16x8 e;
#pragma unroll
                for (int x = 0; x < 4; ++x) {
                    e[x]     = (short)f2bf(v[2 * j][x]);
                    e[4 + x] = (short)f2bf(v[2 * j + 1][x]);
                }
                *reinterpret_cast<bf16x8*>(sA + fswz(r, h * 64 + j * 16)) = e;
            }
#pragma unroll
            for (int c = 0; c < 4; ++c) {
                const int n = nq + c;
                const float* lp = sLut + n * 17;
                unsigned int qq = (unsigned int)q[c];
                bf16x8 w;
#pragma unroll
                for (int p = 0; p < 8; ++p)
                    w[p] = (short)f2bf(lp[(qq >> (4 * p)) & 15]);
                *reinterpret_cast<bf16x8*>(sB + fswz(n, kr * 16)) = w;
            }
        }
        __syncthreads();
#pragma unroll
        for (int kh = 0; kh < 2; ++kh) {
            const int kb = kh * 64 + (lane >> 4) * 16;
            bf16x8 af[4], bfv[4];
#pragma unroll
            for (int i = 0; i < 4; ++i) {
                af[i]  = *reinterpret_cast<const bf16x8*>(sA + fswz(wr * 64 + i * 16 + (lane & 15), kb));
                bfv[i] = *reinterpret_cast<const bf16x8*>(sB + fswz(wc * 64 + i * 16 + (lane & 15), kb));
            }
#pragma unroll
            for (int i = 0; i < 4; ++i)
#pragma unroll
                for (int j = 0; j < 4; ++j)
                    acc[i][j] = __builtin_amdgcn_mfma_f32_16x16x32_bf16(af[i], bfv[j], acc[i][j], 0, 0, 0);
        }
        __syncthreads();
    }
    const int col = lane & 15;
    const int r4  = (lane >> 4) * 4;
#pragma unroll
    for (int i = 0; i < 4; ++i) {
        const int mrow = m0 + wr * 64 + i * 16 + r4;
#pragma unroll
        for (int j = 0; j < 4; ++j) {
            const int ncol = n0 + wc * 64 + j * 16 + col;
#pragma unroll
            for (int r = 0; r < 4; ++r)
                out[(long)(mrow + r) * N + ncol] = acc[i][j][r];
        }
    }
}

extern "C" void kernel_launch(void* const* d_in, const int* in_sizes, int n_in,
                              void* d_out, int out_size, void* d_ws, size_t ws_size,
                              hipStream_t stream) {
    const float* A   = (const float*)d_in[0];
    const int*   Q   = (const int*)d_in[1];
    const float* lut = (const float*)d_in[2];
    float* out = (float*)d_out;

    const long szA = in_sizes[0], szQ = in_sizes[1], szL = in_sizes[2];
    const int N = (int)(szL / 16);
    const int K = (int)(szQ * 8 / N);
    const int M = (int)(szA / K);

    const size_t needA = (size_t)M * K * 2;
    const size_t needW = (size_t)K * N * 2;

    const bool shape_ok = (M % 256 == 0) && (N % 256 == 0) && (K % 128 == 0);

    if (shape_ok && ws_size >= needA + needW) {
        unsigned short* Abf = (unsigned short*)d_ws;
        unsigned short* Wb  = (unsigned short*)((char*)d_ws + needA);
        const long n8 = (long)M * K / 8;
        convA_kernel<<<2048, 256, 0, stream>>>(A, Abf, n8);
        const long tq = (long)(K / 8) * N;
        dequantW_kernel<<<(int)((tq + 255) / 256), 256, 0, stream>>>(Q, lut, Wb, N, tq);
        dim3 grid((M / 256) * (N / 256));
        gemm8p<<<grid, 512, 0, stream>>>(Abf, Wb, out, M, N, K);
    } else {
        dim3 grid(N / FBN, M / FBM);
        sqllm_gemm_fused<<<grid, 256, 0, stream>>>(A, Q, lut, out, M, N, K);
    }
}

// Round 4
// 299.503 us; speedup vs baseline: 1.1706x; 1.0070x over previous
//
#include <hip/hip_runtime.h>
#include <hip/hip_bf16.h>

// sqllm 4-bit GEMM: out[m,n] = sum_k A[m,k] * lut[n, nibble(qweight[k/8,n], k%8)]
// M=8192, N=4096, K=4096. PRE path: A->bf16, W dequant once into ws, then
// 256x256 MFMA GEMM, one phase per 32-k half-tile:
//   12 ds_read_b128 (8A+4B, no B duplication) + 4 global_load_lds (stage H+3)
//   + vmcnt(8) + barrier + 32 MFMA (setprio) + barrier.

typedef __attribute__((ext_vector_type(4))) float  f32x4;
typedef __attribute__((ext_vector_type(4))) int    i32x4;
typedef __attribute__((ext_vector_type(8))) short  bf16x8;

__device__ __forceinline__ unsigned short f2bf(float f) {
    __hip_bfloat16 h = __float2bfloat16(f);
    return __builtin_bit_cast(unsigned short, h);
}

__device__ __forceinline__ void gload16(const unsigned short* g, unsigned short* l) {
    __builtin_amdgcn_global_load_lds(
        (const __attribute__((address_space(1))) unsigned int*)g,
        (__attribute__((address_space(3))) unsigned int*)l, 16, 0, 0);
}

// ---------------- prepass kernels ----------------

__global__ void convA_kernel(const float* __restrict__ in, unsigned short* __restrict__ o, long n8) {
    long i = (long)blockIdx.x * blockDim.x + threadIdx.x;
    long stride = (long)gridDim.x * blockDim.x;
    const f32x4* in4 = reinterpret_cast<const f32x4*>(in);
    bf16x8* o8 = reinterpret_cast<bf16x8*>(o);
    for (; i < n8; i += stride) {
        f32x4 a = in4[2 * i];
        f32x4 b = in4[2 * i + 1];
        bf16x8 e;
#pragma unroll
        for (int x = 0; x < 4; ++x) {
            e[x]     = (short)f2bf(a[x]);
            e[4 + x] = (short)f2bf(b[x]);
        }
        o8[i] = e;
    }
}

// Wb layout: [K/8][N][8] bf16 — prepass write and GEMM staging both coalesced.
__global__ void dequantW_kernel(const int* __restrict__ Q, const float* __restrict__ lut,
                                unsigned short* __restrict__ Wb, int N, long total) {
    long i = (long)blockIdx.x * blockDim.x + threadIdx.x;
    if (i >= total) return;
    unsigned int v = (unsigned int)Q[i];
    int n = (int)(i % N);
    const float* lp = lut + (long)n * 16;
    bf16x8 w;
#pragma unroll
    for (int p = 0; p < 8; ++p)
        w[p] = (short)f2bf(lp[(v >> (4 * p)) & 15]);
    reinterpret_cast<bf16x8*>(Wb)[i] = w;
}

// ---------------- 256x256 GEMM, 1 phase per 32-k half ----------------
// 8 waves (2M x 4N), per-wave 128x64 out. LDS: 4-slot ring of 32-k half-tiles,
// 16KB/slot/matrix. Half H lives in slot H&3. Phase H: read slot H&3, stage
// half H+3 into slot (H+3)&3 (freed by phase H-1), vmcnt(8) guarantees half
// H+1 (read next phase, after this phase's barrier). Never vmcnt(0) in loop.

__global__ __launch_bounds__(512, 2)
void gemm8p(const unsigned short* __restrict__ Abf, const unsigned short* __restrict__ Wb,
            float* __restrict__ out, int M, int N, int K) {
    __shared__ __align__(16) unsigned short sA[4 * 8192];  // 64 KB: 4 slots x 256m x 32k (swizzled)
    __shared__ __align__(16) unsigned short sB[4 * 8192];  // 64 KB: 4 slots x 4kc x 256n x 8

    const int tid  = threadIdx.x;
    const int lane = tid & 63;
    const int wid  = tid >> 6;
    const int wr   = wid >> 2;   // 0..1  (128-row half)
    const int wc   = wid & 3;    // 0..3  (64-col slice)
    const int r15  = lane & 15;
    const int hi   = lane >> 4;

    // XCD-aware bijective swizzle (nwg % 8 == 0 here)
    int nwg = gridDim.x, orig = blockIdx.x;
    int wg = ((nwg & 7) == 0) ? (orig & 7) * (nwg >> 3) + (orig >> 3) : orig;
    const int NBN = N / 256;
    const int m0 = (wg / NBN) * 256, n0 = (wg % NBN) * 256;

    const int NH = K / 32;  // number of 32-k halves (NH % 4 == 0 guaranteed)

    // per-lane ds_read bases (ushort elements)
    // A frag: row = wr*128 + mf*16 + r15, k-octet hi (XOR-swizzled by ((row>>1)&3))
    const int aoff = (wr * 128 + r15) * 32 + ((hi ^ ((r15 >> 1) & 3)) << 3);
    // B frag: [kc=hi][n = wc*64 + nf*16 + r15][8]
    const int boff = hi * 2048 + (wc * 64 + r15) * 8;

    // stage half S (32 k) into ring slot; 4 x gload16/thread (2 A + 2 B)
    auto stage = [&](int S, int slot) {
#pragma unroll
        for (int j = 0; j < 2; ++j) {
            int idx = j * 512 + tid;
            int m = idx >> 2, kc = idx & 3;
            const unsigned short* srcA = Abf + (size_t)(m0 + m) * K + S * 32
                                         + ((kc ^ ((m >> 1) & 3)) << 3);
            gload16(srcA, sA + slot * 8192 + j * 4096 + wid * 512);
            int kc2 = idx >> 8, n = idx & 255;
            const unsigned short* srcB = Wb + ((size_t)(S * 4 + kc2) * N + n0 + n) * 8;
            gload16(srcB, sB + slot * 8192 + j * 4096 + wid * 512);
        }
    };

    f32x4 acc[8][4] = {};

    // prologue: stage halves 0,1,2 (12 loads); vmcnt(8) -> half 0 landed
    stage(0, 0);
    stage(1, 1);
    stage(2, 2);
    asm volatile("s_waitcnt vmcnt(8)" ::: "memory");
    __builtin_amdgcn_s_barrier();

#define PHASE(U) do {                                                             \
    const unsigned short* SA = sA + (U) * 8192;                                   \
    const unsigned short* SB = sB + (U) * 8192;                                   \
    bf16x8 av[8], bv[4];                                                          \
    _Pragma("unroll") for (int nf = 0; nf < 4; ++nf)                              \
        bv[nf] = *(const bf16x8*)(SB + boff + nf * 128);                          \
    _Pragma("unroll") for (int mf = 0; mf < 8; ++mf)                              \
        av[mf] = *(const bf16x8*)(SA + aoff + mf * 512);                          \
    int S = H + (U) + 3; if (S >= NH) S -= NH;                                    \
    stage(S, ((U) + 3) & 3);                                                      \
    asm volatile("s_waitcnt vmcnt(8)" ::: "memory");                              \
    __builtin_amdgcn_s_barrier();                                                 \
    __builtin_amdgcn_s_setprio(1);                                                \
    _Pragma("unroll") for (int mf = 0; mf < 8; ++mf)                              \
        _Pragma("unroll") for (int nf = 0; nf < 4; ++nf)                          \
            acc[mf][nf] = __builtin_amdgcn_mfma_f32_16x16x32_bf16(                \
                av[mf], bv[nf], acc[mf][nf], 0, 0, 0);                            \
    __builtin_amdgcn_s_setprio(0);                                                \
    __builtin_amdgcn_s_barrier();                                                 \
} while (0)

    for (int H = 0; H < NH; H += 4) {
        PHASE(0);
        PHASE(1);
        PHASE(2);
        PHASE(3);
    }
#undef PHASE

    asm volatile("s_waitcnt vmcnt(0)" ::: "memory");  // drain wrap-around prefetches

    // epilogue: C/D layout col=lane&15, row=(lane>>4)*4+reg
#pragma unroll
    for (int mf = 0; mf < 8; ++mf) {
        const int mrow = m0 + wr * 128 + mf * 16 + hi * 4;
#pragma unroll
        for (int nf = 0; nf < 4; ++nf) {
            const int ncol = n0 + wc * 64 + nf * 16 + r15;
            float* po = out + (size_t)mrow * N + ncol;
#pragma unroll
            for (int r = 0; r < 4; ++r) po[(size_t)r * N] = acc[mf][nf][r];
        }
    }
}

// ---------------- fallback fused kernel (small ws only) ----------------

#define FBM 128
#define FBN 128
#define FBK 64

__device__ __forceinline__ int fswz(int row, int kb) {
    return row * (FBK * 2) + (kb ^ ((row & 7) << 4));
}

__global__ __launch_bounds__(256, 2)
void sqllm_gemm_fused(const float* __restrict__ A, const int* __restrict__ Q,
                      const float* __restrict__ lut, float* __restrict__ out,
                      int M, int N, int K) {
    __shared__ __align__(16) char sA[FBM * FBK * 2];
    __shared__ __align__(16) char sB[FBN * FBK * 2];
    __shared__ float sLut[FBN * 17];

    const int tid  = threadIdx.x;
    const int lane = tid & 63;
    const int wid  = tid >> 6;
    const int wr   = wid >> 1;
    const int wc   = wid & 1;
    const int n0 = blockIdx.x * FBN;
    const int m0 = blockIdx.y * FBM;

    for (int i = tid; i < FBN * 16; i += 256) {
        int n = i >> 4, c = i & 15;
        sLut[n * 17 + c] = lut[(long)(n0 + n) * 16 + c];
    }
    __syncthreads();

    f32x4 acc[4][4] = {};
    const int nK = K / FBK;
    for (int kk = 0; kk < nK; ++kk) {
        {
            const int r = tid >> 1, h = tid & 1;
            const float* ap = A + (long)(m0 + r) * K + kk * FBK + h * 32;
            f32x4 v[8];
#pragma unroll
            for (int j = 0; j < 8; ++j) v[j] = reinterpret_cast<const f32x4*>(ap)[j];
            const int kr = tid >> 5, nq = (tid & 31) << 2;
            const int* qp = Q + (long)(kk * (FBK / 8) + kr) * N + n0 + nq;
            i32x4 q = *reinterpret_cast<const i32x4*>(qp);
#pragma unroll
            for (int j = 0; j < 4; ++j) {
                bf16x8 e;
#pragma unroll
                for (int x = 0; x < 4; ++x) {
                    e[x]     = (short)f2bf(v[2 * j][x]);
                    e[4 + x] = (short)f2bf(v[2 * j + 1][x]);
                }
                *reinterpret_cast<bf16x8*>(sA + fswz(r, h * 64 + j * 16)) = e;
            }
#pragma unroll
            for (int c = 0; c < 4; ++c) {
                const int n = nq + c;
                const float* lp = sLut + n * 17;
                unsigned int qq = (unsigned int)q[c];
                bf16x8 w;
#pragma unroll
                for (int p = 0; p < 8; ++p)
                    w[p] = (short)f2bf(lp[(qq >> (4 * p)) & 15]);
                *reinterpret_cast<bf16x8*>(sB + fswz(n, kr * 16)) = w;
            }
        }
        __syncthreads();
#pragma unroll
        for (int kh = 0; kh < 2; ++kh) {
            const int kb = kh * 64 + (lane >> 4) * 16;
            bf16x8 af[4], bfv[4];
#pragma unroll
            for (int i = 0; i < 4; ++i) {
                af[i]  = *reinterpret_cast<const bf16x8*>(sA + fswz(wr * 64 + i * 16 + (lane & 15), kb));
                bfv[i] = *reinterpret_cast<const bf16x8*>(sB + fswz(wc * 64 + i * 16 + (lane & 15), kb));
            }
#pragma unroll
            for (int i = 0; i < 4; ++i)
#pragma unroll
                for (int j = 0; j < 4; ++j)
                    acc[i][j] = __builtin_amdgcn_mfma_f32_16x16x32_bf16(af[i], bfv[j], acc[i][j], 0, 0, 0);
        }
        __syncthreads();
    }
    const int col = lane & 15;
    const int r4  = (lane >> 4) * 4;
#pragma unroll
    for (int i = 0; i < 4; ++i) {
        const int mrow = m0 + wr * 64 + i * 16 + r4;
#pragma unroll
        for (int j = 0; j < 4; ++j) {
            const int ncol = n0 + wc * 64 + j * 16 + col;
#pragma unroll
            for (int r = 0; r < 4; ++r)
                out[(long)(mrow + r) * N + ncol] = acc[i][j][r];
        }
    }
}

extern "C" void kernel_launch(void* const* d_in, const int* in_sizes, int n_in,
                              void* d_out, int out_size, void* d_ws, size_t ws_size,
                              hipStream_t stream) {
    const float* A   = (const float*)d_in[0];
    const int*   Q   = (const int*)d_in[1];
    const float* lut = (const float*)d_in[2];
    float* out = (float*)d_out;

    const long szA = in_sizes[0], szQ = in_sizes[1], szL = in_sizes[2];
    const int N = (int)(szL / 16);
    const int K = (int)(szQ * 8 / N);
    const int M = (int)(szA / K);

    const size_t needA = (size_t)M * K * 2;
    const size_t needW = (size_t)K * N * 2;

    const bool shape_ok = (M % 256 == 0) && (N % 256 == 0) && (K % 128 == 0);

    if (shape_ok && ws_size >= needA + needW) {
        unsigned short* Abf = (unsigned short*)d_ws;
        unsigned short* Wb  = (unsigned short*)((char*)d_ws + needA);
        const long n8 = (long)M * K / 8;
        convA_kernel<<<2048, 256, 0, stream>>>(A, Abf, n8);
        const long tq = (long)(K / 8) * N;
        dequantW_kernel<<<(int)((tq + 255) / 256), 256, 0, stream>>>(Q, lut, Wb, N, tq);
        dim3 grid((M / 256) * (N / 256));
        gemm8p<<<grid, 512, 0, stream>>>(Abf, Wb, out, M, N, K);
    } else {
        dim3 grid(N / FBN, M / FBM);
        sqllm_gemm_fused<<<grid, 256, 0, stream>>>(A, Q, lut, out, M, N, K);
    }
}

// Round 5
// 295.706 us; speedup vs baseline: 1.1856x; 1.0128x over previous
//
#include <hip/hip_runtime.h>
#include <hip/hip_bf16.h>

// sqllm 4-bit GEMM: out[m,n] = sum_k A[m,k] * lut[n, nibble(qweight[k/8,n], k%8)]
// M=8192, N=4096, K=4096. PRE path: A->bf16, W dequant once into ws, then
// 256x256 MFMA GEMM, ONE barrier per 32-k phase, fine ds_read||MFMA interleave:
//   stage 4 gloads -> 6 ds_read -> [2 ds_read | 8 MFMA] x3 -> 8 MFMA
//   -> vmcnt(8) -> s_barrier.   (never vmcnt(0) in the loop)

typedef __attribute__((ext_vector_type(4))) float  f32x4;
typedef __attribute__((ext_vector_type(4))) int    i32x4;
typedef __attribute__((ext_vector_type(8))) short  bf16x8;

__device__ __forceinline__ unsigned short f2bf(float f) {
    __hip_bfloat16 h = __float2bfloat16(f);
    return __builtin_bit_cast(unsigned short, h);
}

__device__ __forceinline__ void gload16(const unsigned short* g, unsigned short* l) {
    __builtin_amdgcn_global_load_lds(
        (const __attribute__((address_space(1))) unsigned int*)g,
        (__attribute__((address_space(3))) unsigned int*)l, 16, 0, 0);
}

// ---------------- prepass kernels ----------------

__global__ void convA_kernel(const float* __restrict__ in, unsigned short* __restrict__ o, long n8) {
    long i = (long)blockIdx.x * blockDim.x + threadIdx.x;
    long stride = (long)gridDim.x * blockDim.x;
    const f32x4* in4 = reinterpret_cast<const f32x4*>(in);
    bf16x8* o8 = reinterpret_cast<bf16x8*>(o);
    for (; i < n8; i += stride) {
        f32x4 a = in4[2 * i];
        f32x4 b = in4[2 * i + 1];
        bf16x8 e;
#pragma unroll
        for (int x = 0; x < 4; ++x) {
            e[x]     = (short)f2bf(a[x]);
            e[4 + x] = (short)f2bf(b[x]);
        }
        o8[i] = e;
    }
}

// Wb layout: [K/8][N][8] bf16 — prepass write and GEMM staging both coalesced.
__global__ void dequantW_kernel(const int* __restrict__ Q, const float* __restrict__ lut,
                                unsigned short* __restrict__ Wb, int N, long total) {
    long i = (long)blockIdx.x * blockDim.x + threadIdx.x;
    if (i >= total) return;
    unsigned int v = (unsigned int)Q[i];
    int n = (int)(i % N);
    const float* lp = lut + (long)n * 16;
    bf16x8 w;
#pragma unroll
    for (int p = 0; p < 8; ++p)
        w[p] = (short)f2bf(lp[(v >> (4 * p)) & 15]);
    reinterpret_cast<bf16x8*>(Wb)[i] = w;
}

// ---------------- 256x256 GEMM, 1 phase / 32-k half, 1 barrier / phase ------
// 8 waves (2M x 4N), per-wave 128x64 out. LDS: 4-slot ring of 32-k half-tiles.
// Half H -> slot H&3. Phase H: stage half H+3 into slot (H+3)&3; read slot H&3
// interleaved with 32 MFMA; vmcnt(8) (-> half H+1 landed) ; barrier.
// RAW: every wave vmcnt(8)+barrier in phase H-1 covers half H.  WAR: all reads
// of a slot finish before the barrier preceding its re-staging.

#define MFMA4(MF, AF) \
    acc[MF][0] = __builtin_amdgcn_mfma_f32_16x16x32_bf16(AF, bv0, acc[MF][0], 0, 0, 0); \
    acc[MF][1] = __builtin_amdgcn_mfma_f32_16x16x32_bf16(AF, bv1, acc[MF][1], 0, 0, 0); \
    acc[MF][2] = __builtin_amdgcn_mfma_f32_16x16x32_bf16(AF, bv2, acc[MF][2], 0, 0, 0); \
    acc[MF][3] = __builtin_amdgcn_mfma_f32_16x16x32_bf16(AF, bv3, acc[MF][3], 0, 0, 0);

__global__ __launch_bounds__(512, 2)
void gemm8p(const unsigned short* __restrict__ Abf, const unsigned short* __restrict__ Wb,
            float* __restrict__ out, int M, int N, int K) {
    __shared__ __align__(16) unsigned short sA[4 * 8192];  // 4 slots x 256m x 32k (kc swizzled)
    __shared__ __align__(16) unsigned short sB[4 * 8192];  // 4 slots x 4kc x 256n x 8

    const int tid  = threadIdx.x;
    const int lane = tid & 63;
    const int wid  = tid >> 6;
    const int wr   = wid >> 2;   // 0..1  (128-row half)
    const int wc   = wid & 3;    // 0..3  (64-col slice)
    const int r15  = lane & 15;
    const int hi   = lane >> 4;

    // XCD-aware bijective swizzle (nwg % 8 == 0 here)
    int nwg = gridDim.x, orig = blockIdx.x;
    int wg = ((nwg & 7) == 0) ? (orig & 7) * (nwg >> 3) + (orig >> 3) : orig;
    const int NBN = N / 256;
    const int m0 = (wg / NBN) * 256, n0 = (wg % NBN) * 256;

    const int NH = K / 32;  // 32-k halves (NH % 4 == 0)

    // per-lane ds_read bases (ushort elements)
    const int aoff = (wr * 128 + r15) * 32 + ((hi ^ ((r15 >> 1) & 3)) << 3);
    const int boff = hi * 2048 + (wc * 64 + r15) * 8;

    // precomputed staging bases: 2 A-loads + 2 B-loads per thread per half.
    // A: idx = j*512+tid -> m = (tid>>2)+j*128, kc = tid&3 (swizzle indep. of j)
    // B: idx -> kc2 = (tid>>8)+2j, n = tid&255
    const int am  = tid >> 2, akc = tid & 3;
    const int akcs = (akc ^ ((am >> 1) & 3)) << 3;
    const unsigned short* baseA0 = Abf + (size_t)(m0 + am) * K + akcs;
    const unsigned short* baseA1 = Abf + (size_t)(m0 + am + 128) * K + akcs;
    const int bkc = tid >> 8, bn = tid & 255;
    const unsigned short* baseB0 = Wb + ((size_t)bkc * N + n0 + bn) * 8;
    const unsigned short* baseB1 = Wb + ((size_t)(bkc + 2) * N + n0 + bn) * 8;
    const size_t bstride = (size_t)32 * N;  // per-half advance for B
    unsigned short* const dA = sA + wid * 512;
    unsigned short* const dB = sB + wid * 512;

    auto stage = [&](int S, int slot) {
        gload16(baseA0 + S * 32, dA + slot * 8192);
        gload16(baseB0 + S * bstride, dB + slot * 8192);
        gload16(baseA1 + S * 32, dA + slot * 8192 + 4096);
        gload16(baseB1 + S * bstride, dB + slot * 8192 + 4096);
    };

    f32x4 acc[8][4] = {};

    // prologue: stage halves 0,1,2 (12 loads); vmcnt(8) -> half 0 landed
    stage(0, 0);
    stage(1, 1);
    stage(2, 2);
    asm volatile("s_waitcnt vmcnt(8)" ::: "memory");
    __builtin_amdgcn_s_barrier();

#define PHASE(U) do {                                                             \
    const unsigned short* SA = sA + (U) * 8192;                                   \
    const unsigned short* SB = sB + (U) * 8192;                                   \
    int S = H + (U) + 3; if (S >= NH) S -= NH;                                    \
    stage(S, ((U) + 3) & 3);                                                      \
    bf16x8 bv0 = *(const bf16x8*)(SB + boff + 0 * 128);                           \
    bf16x8 bv1 = *(const bf16x8*)(SB + boff + 1 * 128);                           \
    bf16x8 bv2 = *(const bf16x8*)(SB + boff + 2 * 128);                           \
    bf16x8 bv3 = *(const bf16x8*)(SB + boff + 3 * 128);                           \
    bf16x8 a0 = *(const bf16x8*)(SA + aoff + 0 * 512);                            \
    bf16x8 a1 = *(const bf16x8*)(SA + aoff + 1 * 512);                            \
    __builtin_amdgcn_s_setprio(1);                                                \
    bf16x8 a2 = *(const bf16x8*)(SA + aoff + 2 * 512);                            \
    bf16x8 a3 = *(const bf16x8*)(SA + aoff + 3 * 512);                            \
    MFMA4(0, a0)                                                                  \
    MFMA4(1, a1)                                                                  \
    bf16x8 a4 = *(const bf16x8*)(SA + aoff + 4 * 512);                            \
    bf16x8 a5 = *(const bf16x8*)(SA + aoff + 5 * 512);                            \
    MFMA4(2, a2)                                                                  \
    MFMA4(3, a3)                                                                  \
    bf16x8 a6 = *(const bf16x8*)(SA + aoff + 6 * 512);                            \
    bf16x8 a7 = *(const bf16x8*)(SA + aoff + 7 * 512);                            \
    MFMA4(4, a4)                                                                  \
    MFMA4(5, a5)                                                                  \
    MFMA4(6, a6)                                                                  \
    MFMA4(7, a7)                                                                  \
    __builtin_amdgcn_s_setprio(0);                                                \
    asm volatile("s_waitcnt vmcnt(8)" ::: "memory");                              \
    __builtin_amdgcn_s_barrier();                                                 \
} while (0)

    for (int H = 0; H < NH; H += 4) {
        PHASE(0);
        PHASE(1);
        PHASE(2);
        PHASE(3);
    }
#undef PHASE

    asm volatile("s_waitcnt vmcnt(0)" ::: "memory");  // drain wrap-around prefetches

    // epilogue: C/D layout col=lane&15, row=(lane>>4)*4+reg
#pragma unroll
    for (int mf = 0; mf < 8; ++mf) {
        const int mrow = m0 + wr * 128 + mf * 16 + hi * 4;
#pragma unroll
        for (int nf = 0; nf < 4; ++nf) {
            const int ncol = n0 + wc * 64 + nf * 16 + r15;
            float* po = out + (size_t)mrow * N + ncol;
#pragma unroll
            for (int r = 0; r < 4; ++r) po[(size_t)r * N] = acc[mf][nf][r];
        }
    }
}

// ---------------- fallback fused kernel (small ws only) ----------------

#define FBM 128
#define FBN 128
#define FBK 64

__device__ __forceinline__ int fswz(int row, int kb) {
    return row * (FBK * 2) + (kb ^ ((row & 7) << 4));
}

__global__ __launch_bounds__(256, 2)
void sqllm_gemm_fused(const float* __restrict__ A, const int* __restrict__ Q,
                      const float* __restrict__ lut, float* __restrict__ out,
                      int M, int N, int K) {
    __shared__ __align__(16) char sA[FBM * FBK * 2];
    __shared__ __align__(16) char sB[FBN * FBK * 2];
    __shared__ float sLut[FBN * 17];

    const int tid  = threadIdx.x;
    const int lane = tid & 63;
    const int wid  = tid >> 6;
    const int wr   = wid >> 1;
    const int wc   = wid & 1;
    const int n0 = blockIdx.x * FBN;
    const int m0 = blockIdx.y * FBM;

    for (int i = tid; i < FBN * 16; i += 256) {
        int n = i >> 4, c = i & 15;
        sLut[n * 17 + c] = lut[(long)(n0 + n) * 16 + c];
    }
    __syncthreads();

    f32x4 acc[4][4] = {};
    const int nK = K / FBK;
    for (int kk = 0; kk < nK; ++kk) {
        {
            const int r = tid >> 1, h = tid & 1;
            const float* ap = A + (long)(m0 + r) * K + kk * FBK + h * 32;
            f32x4 v[8];
#pragma unroll
            for (int j = 0; j < 8; ++j) v[j] = reinterpret_cast<const f32x4*>(ap)[j];
            const int kr = tid >> 5, nq = (tid & 31) << 2;
            const int* qp = Q + (long)(kk * (FBK / 8) + kr) * N + n0 + nq;
            i32x4 q = *reinterpret_cast<const i32x4*>(qp);
#pragma unroll
            for (int j = 0; j < 4; ++j) {
                bf16x8 e;
#pragma unroll
                for (int x = 0; x < 4; ++x) {
                    e[x]     = (short)f2bf(v[2 * j][x]);
                    e[4 + x] = (short)f2bf(v[2 * j + 1][x]);
                }
                *reinterpret_cast<bf16x8*>(sA + fswz(r, h * 64 + j * 16)) = e;
            }
#pragma unroll
            for (int c = 0; c < 4; ++c) {
                const int n = nq + c;
                const float* lp = sLut + n * 17;
                unsigned int qq = (unsigned int)q[c];
                bf16x8 w;
#pragma unroll
                for (int p = 0; p < 8; ++p)
                    w[p] = (short)f2bf(lp[(qq >> (4 * p)) & 15]);
                *reinterpret_cast<bf16x8*>(sB + fswz(n, kr * 16)) = w;
            }
        }
        __syncthreads();
#pragma unroll
        for (int kh = 0; kh < 2; ++kh) {
            const int kb = kh * 64 + (lane >> 4) * 16;
            bf16x8 af[4], bfv[4];
#pragma unroll
            for (int i = 0; i < 4; ++i) {
                af[i]  = *reinterpret_cast<const bf16x8*>(sA + fswz(wr * 64 + i * 16 + (lane & 15), kb));
                bfv[i] = *reinterpret_cast<const bf16x8*>(sB + fswz(wc * 64 + i * 16 + (lane & 15), kb));
            }
#pragma unroll
            for (int i = 0; i < 4; ++i)
#pragma unroll
                for (int j = 0; j < 4; ++j)
                    acc[i][j] = __builtin_amdgcn_mfma_f32_16x16x32_bf16(af[i], bfv[j], acc[i][j], 0, 0, 0);
        }
        __syncthreads();
    }
    const int col = lane & 15;
    const int r4  = (lane >> 4) * 4;
#pragma unroll
    for (int i = 0; i < 4; ++i) {
        const int mrow = m0 + wr * 64 + i * 16 + r4;
#pragma unroll
        for (int j = 0; j < 4; ++j) {
            const int ncol = n0 + wc * 64 + j * 16 + col;
#pragma unroll
            for (int r = 0; r < 4; ++r)
                out[(long)(mrow + r) * N + ncol] = acc[i][j][r];
        }
    }
}

extern "C" void kernel_launch(void* const* d_in, const int* in_sizes, int n_in,
                              void* d_out, int out_size, void* d_ws, size_t ws_size,
                              hipStream_t stream) {
    const float* A   = (const float*)d_in[0];
    const int*   Q   = (const int*)d_in[1];
    const float* lut = (const float*)d_in[2];
    float* out = (float*)d_out;

    const long szA = in_sizes[0], szQ = in_sizes[1], szL = in_sizes[2];
    const int N = (int)(szL / 16);
    const int K = (int)(szQ * 8 / N);
    const int M = (int)(szA / K);

    const size_t needA = (size_t)M * K * 2;
    const size_t needW = (size_t)K * N * 2;

    const bool shape_ok = (M % 256 == 0) && (N % 256 == 0) && (K % 128 == 0);

    if (shape_ok && ws_size >= needA + needW) {
        unsigned short* Abf = (unsigned short*)d_ws;
        unsigned short* Wb  = (unsigned short*)((char*)d_ws + needA);
        const long n8 = (long)M * K / 8;
        convA_kernel<<<2048, 256, 0, stream>>>(A, Abf, n8);
        const long tq = (long)(K / 8) * N;
        dequantW_kernel<<<(int)((tq + 255) / 256), 256, 0, stream>>>(Q, lut, Wb, N, tq);
        dim3 grid((M / 256) * (N / 256));
        gemm8p<<<grid, 512, 0, stream>>>(Abf, Wb, out, M, N, K);
    } else {
        dim3 grid(N / FBN, M / FBM);
        sqllm_gemm_fused<<<grid, 256, 0, stream>>>(A, Q, lut, out, M, N, K);
    }
}

// Round 6
// 294.014 us; speedup vs baseline: 1.1924x; 1.0058x over previous
//
#include <hip/hip_runtime.h>
#include <hip/hip_bf16.h>

// sqllm 4-bit GEMM: out[m,n] = sum_k A[m,k] * lut[n, nibble(qweight[k/8,n], k%8)]
// M=8192, N=4096, K=4096. PRE path: A->bf16, W dequant once into ws, then
// 256x256 MFMA GEMM with CROSS-PHASE REGISTER DOUBLE-BUFFERING:
// phase H consumes fragments loaded during phase H-1; its ds_reads fill the
// alternate register set for phase H+1 while 32 MFMAs run. vmcnt(4)/phase.

typedef __attribute__((ext_vector_type(4))) float  f32x4;
typedef __attribute__((ext_vector_type(4))) int    i32x4;
typedef __attribute__((ext_vector_type(8))) short  bf16x8;

__device__ __forceinline__ unsigned short f2bf(float f) {
    __hip_bfloat16 h = __float2bfloat16(f);
    return __builtin_bit_cast(unsigned short, h);
}

__device__ __forceinline__ void gload16(const unsigned short* g, unsigned short* l) {
    __builtin_amdgcn_global_load_lds(
        (const __attribute__((address_space(1))) unsigned int*)g,
        (__attribute__((address_space(3))) unsigned int*)l, 16, 0, 0);
}

// ---------------- prepass kernels ----------------

__global__ void convA_kernel(const float* __restrict__ in, unsigned short* __restrict__ o, long n8) {
    long i = (long)blockIdx.x * blockDim.x + threadIdx.x;
    long stride = (long)gridDim.x * blockDim.x;
    const f32x4* in4 = reinterpret_cast<const f32x4*>(in);
    bf16x8* o8 = reinterpret_cast<bf16x8*>(o);
    for (; i < n8; i += stride) {
        f32x4 a = in4[2 * i];
        f32x4 b = in4[2 * i + 1];
        bf16x8 e;
#pragma unroll
        for (int x = 0; x < 4; ++x) {
            e[x]     = (short)f2bf(a[x]);
            e[4 + x] = (short)f2bf(b[x]);
        }
        o8[i] = e;
    }
}

// Wb layout: [K/8][N][8] bf16 — prepass write and GEMM staging both coalesced.
__global__ void dequantW_kernel(const int* __restrict__ Q, const float* __restrict__ lut,
                                unsigned short* __restrict__ Wb, int N, long total) {
    long i = (long)blockIdx.x * blockDim.x + threadIdx.x;
    if (i >= total) return;
    unsigned int v = (unsigned int)Q[i];
    int n = (int)(i % N);
    const float* lp = lut + (long)n * 16;
    bf16x8 w;
#pragma unroll
    for (int p = 0; p < 8; ++p)
        w[p] = (short)f2bf(lp[(v >> (4 * p)) & 15]);
    reinterpret_cast<bf16x8*>(Wb)[i] = w;
}

// ---------------- 256x256 GEMM, reg-pipelined phases ----------------
// 8 waves (2M x 4N), per-wave 128x64 out. LDS: 4-slot ring of 32-k half-tiles.
// Half H -> slot H&3. Phase H: stage half H+3 -> slot (H+3)&3; ds_read half
// H+1's fragments (slot (H+1)&3) into the ALTERNATE reg set; 32 MFMA on the
// CURRENT reg set; vmcnt(4) (-> halves H+1,H+2 landed); barrier.
// RAW: vmcnt(4)+barrier at end of H-1 guarantees half H+1 resident when read.
// WAR: phase reads slot (U+1)&3, writes slot (U+3)&3 — disjoint; slot rewrite
// happens >=2 barriers after its last fragment read.

#define LOADFRAGS(NA, NB, SLOT) do {                                              \
    const unsigned short* SA_ = sA + (SLOT) * 8192;                               \
    const unsigned short* SB_ = sB + (SLOT) * 8192;                               \
    _Pragma("unroll") for (int nf = 0; nf < 4; ++nf)                              \
        NB[nf] = *(const bf16x8*)(SB_ + boff + nf * 128);                         \
    _Pragma("unroll") for (int mf = 0; mf < 8; ++mf)                              \
        NA[mf] = *(const bf16x8*)(SA_ + aoff + mf * 512);                         \
} while (0)

#define MFMABLOCK(CA, CB)                                                         \
    _Pragma("unroll") for (int mf = 0; mf < 8; ++mf)                              \
        _Pragma("unroll") for (int nf = 0; nf < 4; ++nf)                          \
            acc[mf][nf] = __builtin_amdgcn_mfma_f32_16x16x32_bf16(                \
                CA[mf], CB[nf], acc[mf][nf], 0, 0, 0);

#define PHASE(U, CA, CB, NA, NB) do {                                             \
    int S = H + (U) + 3; if (S >= NH) S -= NH;                                    \
    stage(S, ((U) + 3) & 3);                                                      \
    LOADFRAGS(NA, NB, ((U) + 1) & 3);                                             \
    __builtin_amdgcn_s_setprio(1);                                                \
    MFMABLOCK(CA, CB)                                                             \
    __builtin_amdgcn_s_setprio(0);                                                \
    asm volatile("s_waitcnt vmcnt(4)" ::: "memory");                              \
    __builtin_amdgcn_s_barrier();                                                 \
} while (0)

__global__ __launch_bounds__(512, 2)
void gemm8p(const unsigned short* __restrict__ Abf, const unsigned short* __restrict__ Wb,
            float* __restrict__ out, int M, int N, int K) {
    __shared__ __align__(16) unsigned short sA[4 * 8192];  // 4 slots x 256m x 32k (kc swizzled)
    __shared__ __align__(16) unsigned short sB[4 * 8192];  // 4 slots x 4kc x 256n x 8

    const int tid  = threadIdx.x;
    const int lane = tid & 63;
    const int wid  = tid >> 6;
    const int wr   = wid >> 2;   // 0..1  (128-row half)
    const int wc   = wid & 3;    // 0..3  (64-col slice)
    const int r15  = lane & 15;
    const int hi   = lane >> 4;

    // XCD-aware bijective swizzle (nwg % 8 == 0 here)
    int nwg = gridDim.x, orig = blockIdx.x;
    int wg = ((nwg & 7) == 0) ? (orig & 7) * (nwg >> 3) + (orig >> 3) : orig;
    const int NBN = N / 256;
    const int m0 = (wg / NBN) * 256, n0 = (wg % NBN) * 256;

    const int NH = K / 32;  // 32-k halves (NH % 4 == 0)

    // per-lane ds_read bases (ushort elements)
    const int aoff = (wr * 128 + r15) * 32 + ((hi ^ ((r15 >> 1) & 3)) << 3);
    const int boff = hi * 2048 + (wc * 64 + r15) * 8;

    // staging bases: 2 A-loads + 2 B-loads per thread per half
    const int am  = tid >> 2, akc = tid & 3;
    const int akcs = (akc ^ ((am >> 1) & 3)) << 3;
    const unsigned short* baseA0 = Abf + (size_t)(m0 + am) * K + akcs;
    const unsigned short* baseA1 = Abf + (size_t)(m0 + am + 128) * K + akcs;
    const int bkc = tid >> 8, bn = tid & 255;
    const unsigned short* baseB0 = Wb + ((size_t)bkc * N + n0 + bn) * 8;
    const unsigned short* baseB1 = Wb + ((size_t)(bkc + 2) * N + n0 + bn) * 8;
    const size_t bstride = (size_t)32 * N;  // per-half advance for B
    unsigned short* const dA = sA + wid * 512;
    unsigned short* const dB = sB + wid * 512;

    auto stage = [&](int S, int slot) {
        gload16(baseA0 + S * 32, dA + slot * 8192);
        gload16(baseB0 + S * bstride, dB + slot * 8192);
        gload16(baseA1 + S * 32, dA + slot * 8192 + 4096);
        gload16(baseB1 + S * bstride, dB + slot * 8192 + 4096);
    };

    f32x4 acc[8][4] = {};
    bf16x8 avA[8], bvA[4], avB[8], bvB[4];

    // prologue: stage halves 0,1,2; vmcnt(4) -> halves 0,1 landed
    stage(0, 0);
    stage(1, 1);
    stage(2, 2);
    asm volatile("s_waitcnt vmcnt(4)" ::: "memory");
    __builtin_amdgcn_s_barrier();
    LOADFRAGS(avA, bvA, 0);  // fragments for half 0

    for (int H = 0; H < NH; H += 4) {
        PHASE(0, avA, bvA, avB, bvB);
        PHASE(1, avB, bvB, avA, bvA);
        PHASE(2, avA, bvA, avB, bvB);
        PHASE(3, avB, bvB, avA, bvA);
    }

    asm volatile("s_waitcnt vmcnt(0)" ::: "memory");  // drain wrap-around prefetches

    // epilogue: C/D layout col=lane&15, row=(lane>>4)*4+reg
#pragma unroll
    for (int mf = 0; mf < 8; ++mf) {
        const int mrow = m0 + wr * 128 + mf * 16 + hi * 4;
#pragma unroll
        for (int nf = 0; nf < 4; ++nf) {
            const int ncol = n0 + wc * 64 + nf * 16 + r15;
            float* po = out + (size_t)mrow * N + ncol;
#pragma unroll
            for (int r = 0; r < 4; ++r) po[(size_t)r * N] = acc[mf][nf][r];
        }
    }
}

#undef PHASE
#undef MFMABLOCK
#undef LOADFRAGS

// ---------------- fallback fused kernel (small ws only) ----------------

#define FBM 128
#define FBN 128
#define FBK 64

__device__ __forceinline__ int fswz(int row, int kb) {
    return row * (FBK * 2) + (kb ^ ((row & 7) << 4));
}

__global__ __launch_bounds__(256, 2)
void sqllm_gemm_fused(const float* __restrict__ A, const int* __restrict__ Q,
                      const float* __restrict__ lut, float* __restrict__ out,
                      int M, int N, int K) {
    __shared__ __align__(16) char sA[FBM * FBK * 2];
    __shared__ __align__(16) char sB[FBN * FBK * 2];
    __shared__ float sLut[FBN * 17];

    const int tid  = threadIdx.x;
    const int lane = tid & 63;
    const int wid  = tid >> 6;
    const int wr   = wid >> 1;
    const int wc   = wid & 1;
    const int n0 = blockIdx.x * FBN;
    const int m0 = blockIdx.y * FBM;

    for (int i = tid; i < FBN * 16; i += 256) {
        int n = i >> 4, c = i & 15;
        sLut[n * 17 + c] = lut[(long)(n0 + n) * 16 + c];
    }
    __syncthreads();

    f32x4 acc[4][4] = {};
    const int nK = K / FBK;
    for (int kk = 0; kk < nK; ++kk) {
        {
            const int r = tid >> 1, h = tid & 1;
            const float* ap = A + (long)(m0 + r) * K + kk * FBK + h * 32;
            f32x4 v[8];
#pragma unroll
            for (int j = 0; j < 8; ++j) v[j] = reinterpret_cast<const f32x4*>(ap)[j];
            const int kr = tid >> 5, nq = (tid & 31) << 2;
            const int* qp = Q + (long)(kk * (FBK / 8) + kr) * N + n0 + nq;
            i32x4 q = *reinterpret_cast<const i32x4*>(qp);
#pragma unroll
            for (int j = 0; j < 4; ++j) {
                bf16x8 e;
#pragma unroll
                for (int x = 0; x < 4; ++x) {
                    e[x]     = (short)f2bf(v[2 * j][x]);
                    e[4 + x] = (short)f2bf(v[2 * j + 1][x]);
                }
                *reinterpret_cast<bf16x8*>(sA + fswz(r, h * 64 + j * 16)) = e;
            }
#pragma unroll
            for (int c = 0; c < 4; ++c) {
                const int n = nq + c;
                const float* lp = sLut + n * 17;
                unsigned int qq = (unsigned int)q[c];
                bf16x8 w;
#pragma unroll
                for (int p = 0; p < 8; ++p)
                    w[p] = (short)f2bf(lp[(qq >> (4 * p)) & 15]);
                *reinterpret_cast<bf16x8*>(sB + fswz(n, kr * 16)) = w;
            }
        }
        __syncthreads();
#pragma unroll
        for (int kh = 0; kh < 2; ++kh) {
            const int kb = kh * 64 + (lane >> 4) * 16;
            bf16x8 af[4], bfv[4];
#pragma unroll
            for (int i = 0; i < 4; ++i) {
                af[i]  = *reinterpret_cast<const bf16x8*>(sA + fswz(wr * 64 + i * 16 + (lane & 15), kb));
                bfv[i] = *reinterpret_cast<const bf16x8*>(sB + fswz(wc * 64 + i * 16 + (lane & 15), kb));
            }
#pragma unroll
            for (int i = 0; i < 4; ++i)
#pragma unroll
                for (int j = 0; j < 4; ++j)
                    acc[i][j] = __builtin_amdgcn_mfma_f32_16x16x32_bf16(af[i], bfv[j], acc[i][j], 0, 0, 0);
        }
        __syncthreads();
    }
    const int col = lane & 15;
    const int r4  = (lane >> 4) * 4;
#pragma unroll
    for (int i = 0; i < 4; ++i) {
        const int mrow = m0 + wr * 64 + i * 16 + r4;
#pragma unroll
        for (int j = 0; j < 4; ++j) {
            const int ncol = n0 + wc * 64 + j * 16 + col;
#pragma unroll
            for (int r = 0; r < 4; ++r)
                out[(long)(mrow + r) * N + ncol] = acc[i][j][r];
        }
    }
}

extern "C" void kernel_launch(void* const* d_in, const int* in_sizes, int n_in,
                              void* d_out, int out_size, void* d_ws, size_t ws_size,
                              hipStream_t stream) {
    const float* A   = (const float*)d_in[0];
    const int*   Q   = (const int*)d_in[1];
    const float* lut = (const float*)d_in[2];
    float* out = (float*)d_out;

    const long szA = in_sizes[0], szQ = in_sizes[1], szL = in_sizes[2];
    const int N = (int)(szL / 16);
    const int K = (int)(szQ * 8 / N);
    const int M = (int)(szA / K);

    const size_t needA = (size_t)M * K * 2;
    const size_t needW = (size_t)K * N * 2;

    const bool shape_ok = (M % 256 == 0) && (N % 256 == 0) && (K % 128 == 0);

    if (shape_ok && ws_size >= needA + needW) {
        unsigned short* Abf = (unsigned short*)d_ws;
        unsigned short* Wb  = (unsigned short*)((char*)d_ws + needA);
        const long n8 = (long)M * K / 8;
        convA_kernel<<<2048, 256, 0, stream>>>(A, Abf, n8);
        const long tq = (long)(K / 8) * N;
        dequantW_kernel<<<(int)((tq + 255) / 256), 256, 0, stream>>>(Q, lut, Wb, N, tq);
        dim3 grid((M / 256) * (N / 256));
        gemm8p<<<grid, 512, 0, stream>>>(Abf, Wb, out, M, N, K);
    } else {
        dim3 grid(N / FBN, M / FBM);
        sqllm_gemm_fused<<<grid, 256, 0, stream>>>(A, Q, lut, out, M, N, K);
    }
}